// Round 2
// baseline (1760.194 us; speedup 1.0000x reference)
//
#include <hip/hip_runtime.h>
#include <math.h>

#define BATCH 8
#define SEQ   512
#define DIM   1024
#define NH    16
#define DHEAD 64

// C[M,N] = A[M,K] @ W[N,K]^T + bias[N]
// A row-major [M,K], W row-major [N,K], C row-major [M,N]
__global__ __launch_bounds__(256) void gemm_bt_kernel(
    const float* __restrict__ A, const float* __restrict__ W,
    const float* __restrict__ bias, float* __restrict__ C,
    int M, int N, int K)
{
    __shared__ float As[16][68];
    __shared__ float Bs[16][68];
    const int tid = threadIdx.x;
    const int bm = blockIdx.y * 64;
    const int bn = blockIdx.x * 64;
    const int ty = tid >> 4;          // 0..15
    const int tx = tid & 15;          // 0..15
    const int lm = tid >> 2;          // 0..63
    const int lk = (tid & 3) << 2;    // 0,4,8,12

    float acc[4][4] = {{0.f,0.f,0.f,0.f},{0.f,0.f,0.f,0.f},
                       {0.f,0.f,0.f,0.f},{0.f,0.f,0.f,0.f}};

    for (int k0 = 0; k0 < K; k0 += 16) {
        float4 av = *reinterpret_cast<const float4*>(&A[(size_t)(bm+lm)*K + k0 + lk]);
        float4 wv = *reinterpret_cast<const float4*>(&W[(size_t)(bn+lm)*K + k0 + lk]);
        As[lk+0][lm]=av.x; As[lk+1][lm]=av.y; As[lk+2][lm]=av.z; As[lk+3][lm]=av.w;
        Bs[lk+0][lm]=wv.x; Bs[lk+1][lm]=wv.y; Bs[lk+2][lm]=wv.z; Bs[lk+3][lm]=wv.w;
        __syncthreads();
        #pragma unroll
        for (int kk = 0; kk < 16; ++kk) {
            float4 a  = *reinterpret_cast<const float4*>(&As[kk][ty<<2]);
            float4 bq = *reinterpret_cast<const float4*>(&Bs[kk][tx<<2]);
            acc[0][0] += a.x*bq.x; acc[0][1] += a.x*bq.y; acc[0][2] += a.x*bq.z; acc[0][3] += a.x*bq.w;
            acc[1][0] += a.y*bq.x; acc[1][1] += a.y*bq.y; acc[1][2] += a.y*bq.z; acc[1][3] += a.y*bq.w;
            acc[2][0] += a.z*bq.x; acc[2][1] += a.z*bq.y; acc[2][2] += a.z*bq.z; acc[2][3] += a.z*bq.w;
            acc[3][0] += a.w*bq.x; acc[3][1] += a.w*bq.y; acc[3][2] += a.w*bq.z; acc[3][3] += a.w*bq.w;
        }
        __syncthreads();
    }
    #pragma unroll
    for (int r = 0; r < 4; ++r) {
        const int row = bm + (ty<<2) + r;
        const int col = bn + (tx<<2);
        float4 o;
        o.x = acc[r][0] + bias[col+0];
        o.y = acc[r][1] + bias[col+1];
        o.z = acc[r][2] + bias[col+2];
        o.w = acc[r][3] + bias[col+3];
        *reinterpret_cast<float4*>(&C[(size_t)row*N + col]) = o;
    }
}

// One block (256 threads) per (b, h, i) query row.
// qh/kh/vh in [B,S,D] layout; head (b,h) row j lives at (b*SEQ+j)*DIM + h*DHEAD.
__global__ __launch_bounds__(256) void attn_kernel(
    const float* __restrict__ qh, const float* __restrict__ kh,
    const float* __restrict__ vh, const float* __restrict__ pdiff,
    const float* __restrict__ gammas, float* __restrict__ concat)
{
    __shared__ float q_s[DHEAD];
    __shared__ float sc[SEQ];    // raw scores, later reweighted scores
    __shared__ float pe[SEQ];    // exp() values (softmax numerators)
    __shared__ float red[256];
    __shared__ float gam_s;

    const int tid = threadIdx.x;
    const int bid = blockIdx.x;
    const int i  = bid & (SEQ - 1);
    const int bh = bid >> 9;           // SEQ = 512
    const int h  = bh & (NH - 1);
    const int b  = bh >> 4;
    const size_t base = (size_t)b * SEQ * DIM + (size_t)h * DHEAD; // + j*DIM
    const float NEG = -1e30f;

    if (tid < DHEAD) q_s[tid] = qh[base + (size_t)i * DIM + tid];
    if (tid == 0)    gam_s = -log1pf(expf(gammas[h]));   // gamma = -softplus
    __syncthreads();

    // ---- raw scores: s = (q . k_j) / sqrt(DH) ----
    for (int j = tid; j < SEQ; j += 256) {
        float s;
        if (j <= i) {
            const float4* kr = reinterpret_cast<const float4*>(&kh[base + (size_t)j * DIM]);
            float accv = 0.f;
            #pragma unroll
            for (int t4 = 0; t4 < 16; ++t4) {
                float4 kv = kr[t4];
                accv += q_s[t4*4+0]*kv.x + q_s[t4*4+1]*kv.y
                      + q_s[t4*4+2]*kv.z + q_s[t4*4+3]*kv.w;
            }
            s = accv * 0.125f;
        } else {
            s = NEG;
        }
        sc[j] = s;
    }
    __syncthreads();

    // ---- first softmax: max ----
    red[tid] = fmaxf(sc[tid], sc[tid + 256]);
    __syncthreads();
    for (int off = 128; off > 0; off >>= 1) {
        if (tid < off) red[tid] = fmaxf(red[tid], red[tid + off]);
        __syncthreads();
    }
    const float mx = red[0];
    __syncthreads();

    // ---- exp + sum ----
    float ea = (tid        <= i) ? expf(sc[tid]       - mx) : 0.f;
    float eb = ((tid + 256) <= i) ? expf(sc[tid + 256] - mx) : 0.f;
    pe[tid] = ea; pe[tid + 256] = eb;
    red[tid] = ea + eb;
    __syncthreads();
    for (int off = 128; off > 0; off >>= 1) {
        if (tid < off) red[tid] += red[tid + off];
        __syncthreads();
    }
    const float T = red[0];
    __syncthreads();
    const float invT = 1.f / T;

    // ---- inclusive cumsum of pe (unnormalized): Hillis-Steele over pair sums ----
    const float ex = pe[2*tid], ey = pe[2*tid + 1];
    const float ps = ex + ey;
    red[tid] = ps;
    __syncthreads();
    for (int off = 1; off < 256; off <<= 1) {
        float add = (tid >= off) ? red[tid - off] : 0.f;
        __syncthreads();
        red[tid] += add;
        __syncthreads();
    }
    const float excl = red[tid] - ps;

    // ---- decay reweight for j = 2t, 2t+1 ----
    const float gam = gam_s;
    float s2a, s2b;
    {
        const int j = 2*tid;
        if (j <= i) {
            float cum = excl + ex;
            float rem = fmaxf(0.f, (T - cum) * invT);
            float dist = sqrtf(rem * (float)(i - j));
            float pd = pdiff[((size_t)b * SEQ + i) * SEQ + j];
            float sg = 1.f / (1.f + expf(-pd));
            float te = expf(dist * gam * expf(sg));
            te = fminf(fmaxf(te, 1e-5f), 1e5f);
            s2a = sc[j] * te;
        } else s2a = NEG;
    }
    {
        const int j = 2*tid + 1;
        if (j <= i) {
            float cum = excl + ex + ey;
            float rem = fmaxf(0.f, (T - cum) * invT);
            float dist = sqrtf(rem * (float)(i - j));
            float pd = pdiff[((size_t)b * SEQ + i) * SEQ + j];
            float sg = 1.f / (1.f + expf(-pd));
            float te = expf(dist * gam * expf(sg));
            te = fminf(fmaxf(te, 1e-5f), 1e5f);
            s2b = sc[j] * te;
        } else s2b = NEG;
    }
    sc[2*tid] = s2a; sc[2*tid + 1] = s2b;
    __syncthreads();

    // ---- second softmax: max ----
    red[tid] = fmaxf(sc[tid], sc[tid + 256]);
    __syncthreads();
    for (int off = 128; off > 0; off >>= 1) {
        if (tid < off) red[tid] = fmaxf(red[tid], red[tid + off]);
        __syncthreads();
    }
    const float mx2 = red[0];
    __syncthreads();

    float fa = (tid        <= i) ? expf(sc[tid]       - mx2) : 0.f;
    float fb = ((tid + 256) <= i) ? expf(sc[tid + 256] - mx2) : 0.f;
    pe[tid] = fa; pe[tid + 256] = fb;
    red[tid] = fa + fb;
    __syncthreads();
    for (int off = 128; off > 0; off >>= 1) {
        if (tid < off) red[tid] += red[tid + off];
        __syncthreads();
    }
    const float invT2 = 1.f / red[0];
    __syncthreads();

    // ---- PV: out[d] = invT2 * sum_j pe[j] * vh[j][d] ----
    {
        const int d = tid & 63;
        const int g = tid >> 6;      // 0..3
        float accv = 0.f;
        for (int j = g; j <= i; j += 4)
            accv += pe[j] * vh[base + (size_t)j * DIM + d];
        red[tid] = accv;
        __syncthreads();
        if (tid < 64) {
            float o = (red[tid] + red[tid + 64] + red[tid + 128] + red[tid + 192]) * invT2;
            if (i == 0) o = 0.f;   // zero_pad: first query row zeroed
            concat[((size_t)b * SEQ + i) * DIM + h * DHEAD + tid] = o;
        }
    }
}

extern "C" void kernel_launch(void* const* d_in, const int* in_sizes, int n_in,
                              void* d_out, int out_size, void* d_ws, size_t ws_size,
                              hipStream_t stream) {
    (void)in_sizes; (void)n_in; (void)out_size; (void)ws_size;
    const float* q      = (const float*)d_in[0];
    const float* k      = (const float*)d_in[1];
    const float* v      = (const float*)d_in[2];
    const float* pdiff  = (const float*)d_in[3];
    const float* Wk     = (const float*)d_in[4];
    const float* bk     = (const float*)d_in[5];
    const float* Wv     = (const float*)d_in[6];
    const float* bv     = (const float*)d_in[7];
    const float* Wo     = (const float*)d_in[8];
    const float* bo     = (const float*)d_in[9];
    const float* gammas = (const float*)d_in[10];
    float* out = (float*)d_out;
    float* ws  = (float*)d_ws;

    const int M = BATCH * SEQ;   // 4096
    const int N = DIM;           // 1024
    const int K = DIM;           // 1024
    float* qh = ws;
    float* kh = ws + (size_t)M * N;
    float* vh = ws + (size_t)2 * M * N;
    float* cc = ws + (size_t)3 * M * N;

    dim3 blk(256);
    dim3 grd(N / 64, M / 64);
    gemm_bt_kernel<<<grd, blk, 0, stream>>>(q, Wk, bk, qh, M, N, K);
    gemm_bt_kernel<<<grd, blk, 0, stream>>>(k, Wk, bk, kh, M, N, K);
    gemm_bt_kernel<<<grd, blk, 0, stream>>>(v, Wv, bv, vh, M, N, K);

    attn_kernel<<<dim3(BATCH * NH * SEQ), blk, 0, stream>>>(qh, kh, vh, pdiff, gammas, cc);

    gemm_bt_kernel<<<grd, blk, 0, stream>>>(cc, Wo, bo, out, M, N, K);
}